// Round 5
// baseline (249.906 us; speedup 1.0000x reference)
//
#include <hip/hip_runtime.h>
#include <hip/hip_bf16.h>
#include <math.h>

#define NN 10000
#define NE 131072

typedef __attribute__((ext_vector_type(8))) short short8;
typedef __attribute__((ext_vector_type(4))) float f32x4;

__device__ __forceinline__ float silu_f(float x) {
    return x / (1.0f + __expf(-x));
}

// round-to-nearest-even f32 -> bf16 (finite inputs only)
__device__ __forceinline__ unsigned short f2bf(float f) {
    unsigned int u = __float_as_uint(f);
    u += 0x7FFFu + ((u >> 16) & 1u);
    return (unsigned short)(u >> 16);
}

// packed pair via HW v_cvt_pk_bf16_f32 (x = low half)
__device__ __forceinline__ unsigned int pk_bf16(float lo, float hi) {
    __hip_bfloat162 h = __float22bfloat162_rn(float2{lo, hi});
    return *reinterpret_cast<unsigned int*>(&h);
}

// ---------------------------------------------------------------------------
// D1: prep (692 blocks).  hist/poscnt/bar already zeroed by D0 memset.
//   [0,40)    node MLP (Ai)
//   [40,80)   prep_W  (fc_W1/2/3 -> bf16 MFMA B-fragments, 10240 elems)
//   [80,592)  prep_B (COALESCED fcW4 read -> scattered Bg write) + histogram
//   [592,692) zero out (600000 floats as float4)
// ---------------------------------------------------------------------------
__global__ __launch_bounds__(256)
void prep_kernel(const int* __restrict__ A,
                 const int* __restrict__ edst,
                 const float* __restrict__ emb_tab,
                 const float* __restrict__ W1, const float* __restrict__ b1,
                 const float* __restrict__ W2, const float* __restrict__ b2,
                 const float* __restrict__ W3, const float* __restrict__ b3,
                 const float* __restrict__ fcW1,
                 const float* __restrict__ fcW2,
                 const float* __restrict__ fcW3,
                 const float* __restrict__ fcW4,
                 int* __restrict__ hist,
                 float* __restrict__ outg,
                 float* __restrict__ Ai,
                 unsigned short* __restrict__ Wg,
                 unsigned short* __restrict__ Bg)
{
    const int blk = blockIdx.x;
    const int tid = threadIdx.x;

    if (blk < 40) {
        // node MLP -> Ai
        int nd = blk * 256 + tid;
        if (nd >= NN) return;
        int a = A[nd];
        float h[16];
#pragma unroll
        for (int i = 0; i < 16; ++i) h[i] = emb_tab[a * 16 + i];
        float h1[64];
#pragma unroll
        for (int j = 0; j < 64; ++j) h1[j] = b1[j];
#pragma unroll
        for (int i = 0; i < 16; ++i) {
            float hv = h[i];
#pragma unroll
            for (int j = 0; j < 64; ++j) h1[j] += hv * W1[i * 64 + j];
        }
#pragma unroll
        for (int j = 0; j < 64; ++j) h1[j] = silu_f(h1[j]);
        float h2[32];
#pragma unroll
        for (int j = 0; j < 32; ++j) h2[j] = b2[j];
#pragma unroll
        for (int i = 0; i < 64; ++i) {
            float hv = h1[i];
#pragma unroll
            for (int j = 0; j < 32; ++j) h2[j] += hv * W2[i * 32 + j];
        }
#pragma unroll
        for (int j = 0; j < 32; ++j) h2[j] = silu_f(h2[j]);
#pragma unroll
        for (int j = 0; j < 8; ++j) {
            float s = b3[j];
#pragma unroll
            for (int i = 0; i < 32; ++i) s += h2[i] * W3[i * 8 + j];
            Ai[nd * 8 + j] = s;
        }
    } else if (blk < 80) {
        // prep_W: 20 frags of 512 bf16. Element (lane,j):
        //   B[k = kf*32 + (lane>>4)*8 + j][col = nt*16 + (lane&15)]
        int i = (blk - 40) * 256 + tid;   // [0, 10240)
        int j    = i & 7;
        int lane = (i >> 3) & 63;
        int f    = i >> 9;
        int q = lane >> 4, n = lane & 15;
        int L, kf, nt;
        if (f < 4)       { L = 1; kf = 0;             nt = f; }
        else if (f < 12) { L = 2; kf = (f - 4) >> 2;  nt = (f - 4) & 3; }
        else             { L = 3; kf = (f - 12) >> 2; nt = (f - 12) & 3; }
        int k = kf * 32 + q * 8 + j;
        int col = nt * 16 + n;
        float v = 0.0f;
        if (L == 1)      { if (k < 10) v = fcW1[k * 64 + col]; }
        else if (L == 2) v = fcW2[k * 64 + col];
        else             v = fcW3[k * 64 + col];
        Wg[i] = f2bf(v);
    } else if (blk < 592) {
        // prep_B inverse-mapped: coalesced fcW4 stream read, scattered Bg
        // write.  Forward map was: Bg[i], i=(k<<11)|(h<<10)|(nt<<9)|(lane<<3)|j,
        // value fcW4[k*1792 + f(uv=h*32+q*8+j, wc=nt*16+n)].  Inverse below.
        // Also: histogram atomicAdd (1:1 edge per thread; hist zeroed by D0).
        int linear = (blk - 80) * 256 + tid;   // [0, 131072)
        atomicAdd(&hist[edst[linear]], 1);
        if (linear < 114688) {                 // 64 * 1792 real elements
            int k = linear / 1792;
            int t = linear - k * 1792;
            int uv, wc;
            if (t < 1024)      { uv = t >> 4;            wc = t & 15; }
            else if (t < 1536) { int r = t - 1024; uv = r >> 3; wc = 16 + (r & 7); }
            else               { int r = t - 1536; uv = r >> 2; wc = 24 + (r & 3); }
            int h  = uv >> 5;
            int q  = (uv >> 3) & 3;
            int j  = uv & 7;
            int nt = wc >> 4;
            int n  = wc & 15;
            int i  = (k << 11) | (h << 10) | (nt << 9) | (((q << 4) | n) << 3) | j;
            Bg[i] = f2bf(fcW4[linear]);
        } else {                               // zero padding: wc in [28,32)
            int z  = linear - 114688;          // [0, 16384)
            int k  = z >> 8;
            int r  = z & 255;
            int uv = r >> 2;
            int c2 = z & 3;                    // wc = 28 + c2 -> nt=1, n=12+c2
            int h  = uv >> 5;
            int q  = (uv >> 3) & 3;
            int j  = uv & 7;
            int i  = (k << 11) | (h << 10) | (1 << 9) | (((q << 4) | (12 + c2)) << 3) | j;
            Bg[i] = 0;
        }
    } else {
        // zero out: 600000 floats = 150000 float4
        int t = (blk - 592) * 256 + tid;   // [0, 25600)
        float4 z = float4{0.f, 0.f, 0.f, 0.f};
        for (int r = t; r < 150000; r += 25600)
            ((float4*)outg)[r] = z;
    }
}

// ---------------------------------------------------------------------------
// D2: scanrank + edge MERGED (512 blocks).  Phase 1: every block redundantly
// scans hist (L2-cached) and ranks its own 256 edges.  Then a hand-rolled
// device barrier (co-residency is exact: 64512 B LDS -> 2 blocks/CU x 256 CU
// = 512 slots; launch_bounds(256,2) caps VGPR at 128).  Phase 2: the fused
// edge pipeline.  Only sortidx crosses the barrier; it is read with
// agent-scope atomic loads.  hist stays intact (counts for the epilogue).
// ---------------------------------------------------------------------------
__global__ __launch_bounds__(256, 2)
void scanrank_edge_kernel(const float* __restrict__ pos,
                          const int* __restrict__ batch,
                          const int* __restrict__ esrc,
                          const int* __restrict__ edst,
                          const float* __restrict__ shifts,
                          const float* __restrict__ cell,
                          const unsigned short* __restrict__ Wg,
                          const unsigned short* __restrict__ Bg,
                          const float* __restrict__ Ai,
                          const int* __restrict__ hist,
                          int* __restrict__ poscnt,
                          int* __restrict__ sortidx,
                          int* __restrict__ bar,
                          float* __restrict__ out_g)
{
    // one 64512 B arena, phase-overlaid:
    //   phase 1: offs[10000] int (40000 B) + part[256] int @40000
    //   phase 2: WBs 20480 | actb 34816 | sdb 1024 | shb 8192
    __shared__ __align__(16) unsigned char SM[64512];

    const int tid = threadIdx.x;

    // ================= phase 1: redundant scan + rank =================
    {
        int* offs = (int*)SM;
        int* part = (int*)(SM + 40000);

        int loc[40];
        int s = 0;
        if (tid < 250) {            // 250*40 = 10000 bins exactly
            const int4* h4 = (const int4*)(hist) + tid * 10;
#pragma unroll
            for (int v = 0; v < 10; ++v) {
                int4 x = h4[v];
                loc[v * 4 + 0] = x.x; loc[v * 4 + 1] = x.y;
                loc[v * 4 + 2] = x.z; loc[v * 4 + 3] = x.w;
                s += x.x + x.y + x.z + x.w;
            }
        } else {
#pragma unroll
            for (int r = 0; r < 40; ++r) loc[r] = 0;
        }
        part[tid] = s;
        __syncthreads();
#pragma unroll
        for (int off = 1; off < 256; off <<= 1) {
            int v = (tid >= off) ? part[tid - off] : 0;
            __syncthreads();
            part[tid] += v;
            __syncthreads();
        }
        if (tid < 250) {
            int run = part[tid] - s;   // exclusive prefix of this chunk
            int base = tid * 40;
#pragma unroll
            for (int r = 0; r < 40; ++r) { offs[base + r] = run; run += loc[r]; }
        }
        __syncthreads();

        int e = blockIdx.x * 256 + tid;
        int d = edst[e];
        int slot = offs[d] + atomicAdd(&poscnt[d], 1);
        sortidx[slot] = e;
    }

    // ================= device barrier (single, lean) =================
    __syncthreads();               // drains each wave's vmcnt -> stores in L2
    if (tid == 0) {
        __threadfence();           // release: writeback this XCD's L2
        __hip_atomic_fetch_add(bar, 1, __ATOMIC_RELAXED,
                               __HIP_MEMORY_SCOPE_AGENT);
        while (__hip_atomic_load(bar, __ATOMIC_RELAXED,
                                 __HIP_MEMORY_SCOPE_AGENT) < (int)gridDim.x)
            __builtin_amdgcn_s_sleep(2);
        __threadfence();           // acquire: invalidate stale L2 lines
    }
    __syncthreads();

    // ================= phase 2: fused edge pipeline =================
    unsigned char* WBs = SM;                                        // 20480
    unsigned short (*actb)[64 * 68] =
        (unsigned short (*)[64 * 68])(SM + 20480);                  // 34816
    int*   sdb = (int*)(SM + 20480 + 34816);                        // 1024
    float (*shb)[64 * 8] =
        (float (*)[64 * 8])(SM + 20480 + 34816 + 1024);             // 8192

    const int wave = tid >> 6;
    const int lane = tid & 63;
    const int q    = lane >> 4;
    const int n    = lane & 15;
    const int i    = blockIdx.x * 256 + wave * 64 + lane;

    // ---- stage weight fragments (block-shared, 1280 x 16B) ----
#pragma unroll
    for (int it = 0; it < 5; ++it) {
        int idx = it * 256 + tid;
        const unsigned short* gp = Wg + idx * 8;
        unsigned char* lb = WBs + (it * 256 + wave * 64) * 16;
        __builtin_amdgcn_global_load_lds(
            (const __attribute__((address_space(1))) unsigned int*)gp,
            (__attribute__((address_space(3))) unsigned int*)lb, 16, 0, 0);
    }

    unsigned short* actw = actb[wave];

    // ---- geometry (1 lane = 1 edge); sortidx via agent-scope load ----
    int e = __hip_atomic_load(&sortidx[i], __ATOMIC_RELAXED,
                              __HIP_MEMORY_SCOPE_AGENT);
    int s = esrc[e], d = edst[e];
    sdb[wave * 64 + lane] = s | (d << 16);
    int b = batch[s];
    const float* C = cell + b * 9;
    float sx = shifts[e * 3 + 0], sy = shifts[e * 3 + 1], sz = shifts[e * 3 + 2];
    float vx = pos[d * 3 + 0] - pos[s * 3 + 0] + sx * C[0] + sy * C[3] + sz * C[6];
    float vy = pos[d * 3 + 1] - pos[s * 3 + 1] + sx * C[1] + sy * C[4] + sz * C[7];
    float vz = pos[d * 3 + 2] - pos[s * 3 + 2] + sx * C[2] + sy * C[5] + sz * C[8];
    float len = sqrtf(vx * vx + vy * vy + vz * vz);
    float inv = 1.0f / fmaxf(len, 1e-9f);
    float ux = vx * inv, uy = vy * inv, uz = vz * inv;
    {
        const float s3c  = 1.7320508075688772f;
        const float s5c  = 2.2360679774997896f;
        const float s15c = 3.872983346207417f;
        float* shw = shb[wave];
        *(float4*)&shw[lane * 8]     = float4{s3c * ux, s3c * uy, s3c * uz,
                                              s15c * ux * uz};
        *(float4*)&shw[lane * 8 + 4] = float4{s15c * ux * uy,
                                              s5c * (uy * uy - 0.5f * (ux * ux + uz * uz)),
                                              s15c * uy * uz,
                                              0.5f * s15c * (uz * uz - ux * ux)};
    }

    // soft_one_hot (sqrt(10) cancels with fc_W1's /sqrt(10))
    float embv[10];
    float base = len * 2.75f;
#pragma unroll
    for (int ii = 0; ii < 10; ++ii) {
        float ddv = base - (float)(ii + 1);
        embv[ii] = __expf(-ddv * ddv) * (1.0f / 1.12f);
    }
    {
        unsigned int u0 = pk_bf16(embv[0], embv[1]);
        unsigned int u1 = pk_bf16(embv[2], embv[3]);
        unsigned int u2 = pk_bf16(embv[4], embv[5]);
        unsigned int u3 = pk_bf16(embv[6], embv[7]);
        unsigned int u4 = pk_bf16(embv[8], embv[9]);
        uint2* arow = (uint2*)&actw[lane * 68];
        arow[0] = uint2{u0, u1};
        arow[1] = uint2{u2, u3};
        arow[2] = uint2{u4, 0u};
        arow[3] = uint2{0u, 0u};
        arow[4] = uint2{0u, 0u};
        arow[5] = uint2{0u, 0u};
        arow[6] = uint2{0u, 0u};
        arow[7] = uint2{0u, 0u};
    }

    __syncthreads();   // weights staged; sdb written

    union AF { unsigned int u[4]; short8 s8; };
    const f32x4 Z4 = (f32x4){0.f, 0.f, 0.f, 0.f};
    const unsigned short* Wbuf = (const unsigned short*)WBs;

    auto loadA = [&](int t, int kf) -> AF {
        const unsigned short* ap = &actw[(t * 16 + n) * 68 + kf * 32 + q * 8];
        uint2 a = *(const uint2*)ap;
        uint2 c = *(const uint2*)(ap + 4);
        AF f; f.u[0] = a.x; f.u[1] = a.y; f.u[2] = c.x; f.u[3] = c.y;
        return f;
    };
    auto loadW = [&](int f) -> short8 {
        return *(const short8*)&Wbuf[(f * 64 + lane) * 8];
    };

    // ---- layer 1: K=32 (padded emb), N=64 ----
    {
        AF A1[4];
#pragma unroll
        for (int t = 0; t < 4; ++t) A1[t] = loadA(t, 0);
#pragma unroll
        for (int nt = 0; nt < 4; ++nt) {
            short8 W0 = loadW(nt);
            f32x4 Cc[4];
#pragma unroll
            for (int t = 0; t < 4; ++t)
                Cc[t] = __builtin_amdgcn_mfma_f32_16x16x32_bf16(A1[t].s8, W0, Z4, 0, 0, 0);
#pragma unroll
            for (int t = 0; t < 4; ++t)
#pragma unroll
                for (int r = 0; r < 4; ++r)
                    actw[(t * 16 + q * 4 + r) * 68 + nt * 16 + n] = f2bf(silu_f(Cc[t][r]));
        }
    }

    // ---- layer 2: K=64 ----
    {
        AF A2[4][2];
#pragma unroll
        for (int t = 0; t < 4; ++t)
#pragma unroll
            for (int kf = 0; kf < 2; ++kf) A2[t][kf] = loadA(t, kf);
#pragma unroll
        for (int nt = 0; nt < 4; ++nt) {
            short8 Wk0 = loadW(4 + nt);
            short8 Wk1 = loadW(8 + nt);
            f32x4 Cc[4];
#pragma unroll
            for (int t = 0; t < 4; ++t) {
                Cc[t] = __builtin_amdgcn_mfma_f32_16x16x32_bf16(A2[t][0].s8, Wk0, Z4, 0, 0, 0);
                Cc[t] = __builtin_amdgcn_mfma_f32_16x16x32_bf16(A2[t][1].s8, Wk1, Cc[t], 0, 0, 0);
            }
#pragma unroll
            for (int t = 0; t < 4; ++t)
#pragma unroll
                for (int r = 0; r < 4; ++r)
                    actw[(t * 16 + q * 4 + r) * 68 + nt * 16 + n] = f2bf(silu_f(Cc[t][r] * 0.125f));
        }
    }

    // ---- layer 3: K=64, epilogue -> w3 transposed [k][edge] in actw ----
    {
        AF A3[4][2];
#pragma unroll
        for (int t = 0; t < 4; ++t)
#pragma unroll
            for (int kf = 0; kf < 2; ++kf) A3[t][kf] = loadA(t, kf);
#pragma unroll
        for (int nt = 0; nt < 4; ++nt) {
            short8 Wk0 = loadW(12 + nt);
            short8 Wk1 = loadW(16 + nt);
            f32x4 Cc[4];
#pragma unroll
            for (int t = 0; t < 4; ++t) {
                Cc[t] = __builtin_amdgcn_mfma_f32_16x16x32_bf16(A3[t][0].s8, Wk0, Z4, 0, 0, 0);
                Cc[t] = __builtin_amdgcn_mfma_f32_16x16x32_bf16(A3[t][1].s8, Wk1, Cc[t], 0, 0, 0);
            }
#pragma unroll
            for (int t = 0; t < 4; ++t)
#pragma unroll
                for (int r = 0; r < 4; ++r)
                    actw[(nt * 16 + n) * 68 + t * 16 + q * 4 + r] = f2bf(silu_f(Cc[t][r] * 0.125f));
        }
    }

    __syncthreads();   // all waves done with Wbuf -> WBs reusable as B dbuf

    auto stageB = [&](int c, int buf) {
#pragma unroll
        for (int it = 0; it < 2; ++it) {
            int idx = it * 256 + tid;
            const unsigned char* gp = ((const unsigned char*)Bg) + c * 8192 + idx * 16;
            unsigned char* lb = WBs + buf * 8192 + (it * 256 + wave * 64) * 16;
            __builtin_amdgcn_global_load_lds(
                (const __attribute__((address_space(1))) unsigned int*)gp,
                (__attribute__((address_space(3))) unsigned int*)lb, 16, 0, 0);
        }
    };
    stageB(0, 0);

    // k-invariant P fragments: P[e, uv=h*32+q*8+j] = As[h*4+q]*Ad[j]
    AF P[4][2];
#pragma unroll
    for (int t = 0; t < 4; ++t) {
        int eL = wave * 64 + t * 16 + n;
        int sd = sdb[eL];
        int ss  = sd & 0xFFFF;
        int dd2 = sd >> 16;
        float As0 = Ai[ss * 8 + q];
        float As1 = Ai[ss * 8 + 4 + q];
        float4 d0 = *(const float4*)&Ai[dd2 * 8];
        float4 d1 = *(const float4*)&Ai[dd2 * 8 + 4];
        float Ad[8] = {d0.x, d0.y, d0.z, d0.w, d1.x, d1.y, d1.z, d1.w};
#pragma unroll
        for (int h = 0; h < 2; ++h) {
            float s0 = h ? As1 : As0;
            P[t][h].u[0] = pk_bf16(s0 * Ad[0], s0 * Ad[1]);
            P[t][h].u[1] = pk_bf16(s0 * Ad[2], s0 * Ad[3]);
            P[t][h].u[2] = pk_bf16(s0 * Ad[4], s0 * Ad[5]);
            P[t][h].u[3] = pk_bf16(s0 * Ad[6], s0 * Ad[7]);
        }
    }

    f32x4 out[4][2];
#pragma unroll
    for (int t = 0; t < 4; ++t)
#pragma unroll
        for (int nt = 0; nt < 2; ++nt)
            out[t][nt] = (f32x4){0.f, 0.f, 0.f, 0.f};

    __syncthreads();   // chunk 0 resident

#pragma unroll 1
    for (int c = 0; c < 32; ++c) {
        int cur = c & 1;
        if (c < 31) stageB(c + 1, cur ^ 1);
#pragma unroll
        for (int kk = 0; kk < 2; ++kk) {
            int k = c * 2 + kk;
            short8 Bf[2][2];
#pragma unroll
            for (int h = 0; h < 2; ++h)
#pragma unroll
                for (int nt = 0; nt < 2; ++nt)
                    Bf[h][nt] = *(const short8*)(WBs + cur * 8192 +
                                 ((kk * 2 + h) * 2 + nt) * 1024 + lane * 16);
#pragma unroll
            for (int t = 0; t < 4; ++t) {
                uint2 v = *(const uint2*)&actw[k * 68 + t * 16 + q * 4];
                float w0 = __uint_as_float(v.x << 16);
                float w1 = __uint_as_float(v.x & 0xFFFF0000u);
                float w2 = __uint_as_float(v.y << 16);
                float w3 = __uint_as_float(v.y & 0xFFFF0000u);
#pragma unroll
                for (int nt = 0; nt < 2; ++nt) {
                    f32x4 Q = __builtin_amdgcn_mfma_f32_16x16x32_bf16(
                        P[t][0].s8, Bf[0][nt], Z4, 0, 0, 0);
                    Q = __builtin_amdgcn_mfma_f32_16x16x32_bf16(
                        P[t][1].s8, Bf[1][nt], Q, 0, 0, 0);
                    out[t][nt][0] += w0 * Q[0];
                    out[t][nt][1] += w1 * Q[1];
                    out[t][nt][2] += w2 * Q[2];
                    out[t][nt][3] += w3 * Q[3];
                }
            }
        }
        __syncthreads();
    }

    // ---- epilogue: feat rows -> LDS (stride 33), per-wave segmented
    // reduction using the precomputed sh table ----
    float* featL = (float*)actw;   // [64][33] fp32 = 8448 B
#pragma unroll
    for (int t = 0; t < 4; ++t) {
#pragma unroll
        for (int r = 0; r < 4; ++r) {
            int row = t * 16 + q * 4 + r;
            featL[row * 33 + n]      = out[t][0][r];
            featL[row * 33 + 16 + n] = out[t][1][r];
        }
    }
    // same-wave ds write->read: lockstep + compiler lgkmcnt, no barrier needed

    if (lane < 60) {
        int j = lane;
        int cc, sidx = 0;
        bool is0 = (j < 16);
        if (j < 16)      { cc = j; }
        else if (j < 40) { cc = 16 + (j - 16) / 3; sidx = (j - 16) % 3; }
        else             { cc = 24 + (j - 40) / 5; sidx = 3 + (j - 40) % 5; }

        const float* shw = shb[wave];
        int cur_d = sdb[wave * 64] >> 16;
        float acc = 0.f;
        for (int e2 = 0; e2 < 64; ++e2) {
            int d_e = sdb[wave * 64 + e2] >> 16;   // wave-uniform
            if (d_e != cur_d) {
                int cnt = hist[cur_d];
                atomicAdd(&out_g[cur_d * 60 + j], acc * (1.0f / 64.0f) / (float)cnt);
                acc = 0.f;
                cur_d = d_e;
            }
            float f  = featL[e2 * 33 + cc];
            float sh = shw[e2 * 8 + sidx];
            if (is0) sh = 1.0f;
            acc += f * sh;
        }
        int cnt = hist[cur_d];
        atomicAdd(&out_g[cur_d * 60 + j], acc * (1.0f / 64.0f) / (float)cnt);
    }
}

extern "C" void kernel_launch(void* const* d_in, const int* in_sizes, int n_in,
                              void* d_out, int out_size, void* d_ws, size_t ws_size,
                              hipStream_t stream)
{
    const float* pos     = (const float*)d_in[0];
    const int*   A       = (const int*)d_in[1];
    const int*   batch   = (const int*)d_in[2];
    const int*   esrc    = (const int*)d_in[3];
    const int*   edst    = (const int*)d_in[4];
    const float* shifts  = (const float*)d_in[5];
    const float* cell    = (const float*)d_in[6];
    const float* emb_tab = (const float*)d_in[7];
    const float* fitW1   = (const float*)d_in[8];
    const float* fitb1   = (const float*)d_in[9];
    const float* fitW2   = (const float*)d_in[10];
    const float* fitb2   = (const float*)d_in[11];
    const float* fitW3   = (const float*)d_in[12];
    const float* fitb3   = (const float*)d_in[13];
    const float* fcW1    = (const float*)d_in[14];
    const float* fcW2    = (const float*)d_in[15];
    const float* fcW3    = (const float*)d_in[16];
    const float* fcW4    = (const float*)d_in[17];

    float* out = (float*)d_out;

    // workspace layout (all 16B-aligned; hist/poscnt/bar adjacent so one
    // memset covers them)
    char* W = (char*)d_ws;
    float* Ai      = (float*)W;  W += (size_t)NN * 8 * 4;        // 320000
    int* sortidx   = (int*)W;    W += (size_t)NE * 4;            // 524288
    int* hist      = (int*)W;    W += (size_t)NN * 4;            // 40000
    int* poscnt    = (int*)W;    W += (size_t)NN * 4;            // 40000
    int* bar       = (int*)W;    W += 16;                        // 16
    unsigned short* Bg = (unsigned short*)W; W += (size_t)131072 * 2;
    unsigned short* Wg = (unsigned short*)W; W += (size_t)10240 * 2;

    // D0: zero hist + poscnt + bar (contiguous, one memset)
    hipMemsetAsync(hist, 0, (size_t)NN * 4 * 2 + 16, stream);

    // D1: prep (MLP, W/B fragment packing, histogram, out zeroing)
    prep_kernel<<<692, 256, 0, stream>>>(
        A, edst, emb_tab, fitW1, fitb1, fitW2, fitb2, fitW3, fitb3,
        fcW1, fcW2, fcW3, fcW4, hist, out, Ai, Wg, Bg);

    // D2: merged scan+rank -> device barrier -> edge pipeline
    scanrank_edge_kernel<<<NE / 256, 256, 0, stream>>>(
        pos, batch, esrc, edst, shifts, cell, Wg, Bg,
        Ai, hist, poscnt, sortidx, bar, out);
}

// Round 6
// 243.909 us; speedup vs baseline: 1.0246x; 1.0246x over previous
//
#include <hip/hip_runtime.h>
#include <hip/hip_bf16.h>
#include <math.h>

#define NN 10000
#define NE 131072

typedef __attribute__((ext_vector_type(8))) short short8;
typedef __attribute__((ext_vector_type(4))) float f32x4;

__device__ __forceinline__ float silu_f(float x) {
    return x / (1.0f + __expf(-x));
}

// round-to-nearest-even f32 -> bf16 (finite inputs only)
__device__ __forceinline__ unsigned short f2bf(float f) {
    unsigned int u = __float_as_uint(f);
    u += 0x7FFFu + ((u >> 16) & 1u);
    return (unsigned short)(u >> 16);
}

// packed pair via HW v_cvt_pk_bf16_f32 (x = low half)
__device__ __forceinline__ unsigned int pk_bf16(float lo, float hi) {
    __hip_bfloat162 h = __float22bfloat162_rn(float2{lo, hi});
    return *reinterpret_cast<unsigned int*>(&h);
}

// write-through store (agent-scope, relaxed): lands at the coherence point,
// no dirty local-L2 line -> cross-XCD visible after vmcnt drain, NO fence.
__device__ __forceinline__ void st_wt_f32(float* p, float v) {
    __hip_atomic_store(p, v, __ATOMIC_RELAXED, __HIP_MEMORY_SCOPE_AGENT);
}
__device__ __forceinline__ void st_wt_u32(unsigned int* p, unsigned int v) {
    __hip_atomic_store(p, v, __ATOMIC_RELAXED, __HIP_MEMORY_SCOPE_AGENT);
}
__device__ __forceinline__ void st_wt_i32(int* p, int v) {
    __hip_atomic_store(p, v, __ATOMIC_RELAXED, __HIP_MEMORY_SCOPE_AGENT);
}

// ---------------------------------------------------------------------------
// MEGA2: one kernel, 512 blocks x 256 thr, LDS 64512 B -> exactly 2 blocks/CU
// (co-residency proven by round-5's passing run of the same grid shape).
//   phase A: prep (MLP->Ai, Wg, Bg, histogram) -- all outputs write-through
//   bar[0]  : fence-free device barrier (vmcnt drained by __syncthreads)
//   phase B: redundant per-block scan of hist + rank -> sortidx (write-through)
//   bar[1]  : fence-free device barrier
//   phase C: fused edge pipeline (identical to the verified round-5 phase 2)
// out zeroing + hist/poscnt/bar zeroing are done by two preceding memsets.
// ---------------------------------------------------------------------------
__global__ __launch_bounds__(256, 2)
void mega2_kernel(const float* __restrict__ pos,
                  const int* __restrict__ A,
                  const int* __restrict__ batch,
                  const int* __restrict__ esrc,
                  const int* __restrict__ edst,
                  const float* __restrict__ shifts,
                  const float* __restrict__ cell,
                  const float* __restrict__ emb_tab,
                  const float* __restrict__ W1, const float* __restrict__ b1,
                  const float* __restrict__ W2, const float* __restrict__ b2,
                  const float* __restrict__ W3, const float* __restrict__ b3,
                  const float* __restrict__ fcW1,
                  const float* __restrict__ fcW2,
                  const float* __restrict__ fcW3,
                  const float* __restrict__ fcW4,
                  int* __restrict__ hist,
                  int* __restrict__ poscnt,
                  int* __restrict__ bar,
                  float* __restrict__ Ai,
                  unsigned short* __restrict__ Wg,
                  unsigned short* __restrict__ Bg,
                  int* __restrict__ sortidx,
                  float* __restrict__ out_g)
{
    // one 64512 B arena, phase-overlaid:
    //   phase B: offs[10000] int (40000 B) + part[256] int @40000
    //   phase C: WBs 20480 | actb 34816 | sdb 1024 | shb 8192
    __shared__ __align__(16) unsigned char SM[64512];

    const int tid = threadIdx.x;
    const int blk = blockIdx.x;

    // ================= phase A: prep (316 virtual blocks) =================
    if (blk < 40) {
        // node MLP -> Ai (write-through scalar stores)
        int nd = blk * 256 + tid;
        if (nd < NN) {
            int a = A[nd];
            float h[16];
#pragma unroll
            for (int i = 0; i < 16; ++i) h[i] = emb_tab[a * 16 + i];
            float h1[64];
#pragma unroll
            for (int j = 0; j < 64; ++j) h1[j] = b1[j];
#pragma unroll
            for (int i = 0; i < 16; ++i) {
                float hv = h[i];
#pragma unroll
                for (int j = 0; j < 64; ++j) h1[j] += hv * W1[i * 64 + j];
            }
#pragma unroll
            for (int j = 0; j < 64; ++j) h1[j] = silu_f(h1[j]);
            float h2[32];
#pragma unroll
            for (int j = 0; j < 32; ++j) h2[j] = b2[j];
#pragma unroll
            for (int i = 0; i < 64; ++i) {
                float hv = h1[i];
#pragma unroll
                for (int j = 0; j < 32; ++j) h2[j] += hv * W2[i * 32 + j];
            }
#pragma unroll
            for (int j = 0; j < 32; ++j) h2[j] = silu_f(h2[j]);
#pragma unroll
            for (int j = 0; j < 8; ++j) {
                float s = b3[j];
#pragma unroll
                for (int i = 0; i < 32; ++i) s += h2[i] * W3[i * 8 + j];
                st_wt_f32(&Ai[nd * 8 + j], s);
            }
        }
    } else if (blk < 60) {
        // prep_W paired: thread t -> elements i0=2t, i0+1 (same lane/f, j0,j0+1)
        int t  = (blk - 40) * 256 + tid;   // [0, 5120)
        int i0 = 2 * t;
        int j0   = i0 & 7;                 // even
        int lane = (i0 >> 3) & 63;
        int f    = i0 >> 9;
        int q = lane >> 4, n = lane & 15;
        int L, kf, nt;
        if (f < 4)       { L = 1; kf = 0;             nt = f; }
        else if (f < 12) { L = 2; kf = (f - 4) >> 2;  nt = (f - 4) & 3; }
        else             { L = 3; kf = (f - 12) >> 2; nt = (f - 12) & 3; }
        int col = nt * 16 + n;
        float v0 = 0.0f, v1 = 0.0f;
        int k0 = kf * 32 + q * 8 + j0;
        int k1 = k0 + 1;
        if (L == 1)      { if (k0 < 10) v0 = fcW1[k0 * 64 + col];
                           if (k1 < 10) v1 = fcW1[k1 * 64 + col]; }
        else if (L == 2) { v0 = fcW2[k0 * 64 + col]; v1 = fcW2[k1 * 64 + col]; }
        else             { v0 = fcW3[k0 * 64 + col]; v1 = fcW3[k1 * 64 + col]; }
        unsigned int pack = (unsigned int)f2bf(v0) | ((unsigned int)f2bf(v1) << 16);
        st_wt_u32((unsigned int*)(Wg + i0), pack);
    } else if (blk < 316) {
        // prep_B paired + histogram (2 edges / thread)
        int t = (blk - 60) * 256 + tid;    // [0, 65536)
        int2 dd = ((const int2*)edst)[t];
        atomicAdd(&hist[dd.x], 1);
        atomicAdd(&hist[dd.y], 1);

        int i0 = 2 * t;
        int j0   = i0 & 7;                 // even
        int lane = (i0 >> 3) & 63;
        int nt   = (i0 >> 9) & 1;
        int h    = (i0 >> 10) & 1;
        int k    = i0 >> 11;
        int q = lane >> 4, n = lane & 15;
        int wc  = nt * 16 + n;
        int uv0 = h * 32 + q * 8 + j0;
        int uv1 = uv0 + 1;
        float v0 = 0.0f, v1 = 0.0f;
        if (wc < 16)      { v0 = fcW4[k * 1792 + uv0 * 16 + wc];
                            v1 = fcW4[k * 1792 + uv1 * 16 + wc]; }
        else if (wc < 24) { v0 = fcW4[k * 1792 + 1024 + uv0 * 8 + (wc - 16)];
                            v1 = fcW4[k * 1792 + 1024 + uv1 * 8 + (wc - 16)]; }
        else if (wc < 28) { v0 = fcW4[k * 1792 + 1536 + uv0 * 4 + (wc - 24)];
                            v1 = fcW4[k * 1792 + 1536 + uv1 * 4 + (wc - 24)]; }
        // wc in [28,32): both stay 0 (padding)
        unsigned int pack = (unsigned int)f2bf(v0) | ((unsigned int)f2bf(v1) << 16);
        st_wt_u32((unsigned int*)(Bg + i0), pack);
    }
    // blocks [316,512): no phase-A work -> straight to the barrier

    // ================= barrier A->B (fence-free) =================
    // __syncthreads drains each wave's vmcnt -> all this block's write-through
    // stores + atomics have reached the coherence point before tid0 signals.
    __syncthreads();
    if (tid == 0) {
        __hip_atomic_fetch_add(&bar[0], 1, __ATOMIC_RELAXED,
                               __HIP_MEMORY_SCOPE_AGENT);
        while (__hip_atomic_load(&bar[0], __ATOMIC_RELAXED,
                                 __HIP_MEMORY_SCOPE_AGENT) < (int)gridDim.x)
            __builtin_amdgcn_s_sleep(2);
    }
    __syncthreads();

    // ================= phase B: redundant scan + rank =================
    {
        int* offs = (int*)SM;
        int* part = (int*)(SM + 40000);

        int loc[40];
        int s = 0;
        if (tid < 250) {            // 250*40 = 10000 bins exactly
            const int4* h4 = (const int4*)(hist) + tid * 10;
#pragma unroll
            for (int v = 0; v < 10; ++v) {
                int4 x = h4[v];
                loc[v * 4 + 0] = x.x; loc[v * 4 + 1] = x.y;
                loc[v * 4 + 2] = x.z; loc[v * 4 + 3] = x.w;
                s += x.x + x.y + x.z + x.w;
            }
        } else {
#pragma unroll
            for (int r = 0; r < 40; ++r) loc[r] = 0;
        }
        part[tid] = s;
        __syncthreads();
#pragma unroll
        for (int off = 1; off < 256; off <<= 1) {
            int v = (tid >= off) ? part[tid - off] : 0;
            __syncthreads();
            part[tid] += v;
            __syncthreads();
        }
        if (tid < 250) {
            int run = part[tid] - s;   // exclusive prefix of this chunk
            int base = tid * 40;
#pragma unroll
            for (int r = 0; r < 40; ++r) { offs[base + r] = run; run += loc[r]; }
        }
        __syncthreads();

        int e = blk * 256 + tid;
        int d = edst[e];
        int slot = offs[d] + atomicAdd(&poscnt[d], 1);
        st_wt_i32(&sortidx[slot], e);      // write-through: no fence needed
    }

    // ================= barrier B->C (fence-free) =================
    __syncthreads();
    if (tid == 0) {
        __hip_atomic_fetch_add(&bar[1], 1, __ATOMIC_RELAXED,
                               __HIP_MEMORY_SCOPE_AGENT);
        while (__hip_atomic_load(&bar[1], __ATOMIC_RELAXED,
                                 __HIP_MEMORY_SCOPE_AGENT) < (int)gridDim.x)
            __builtin_amdgcn_s_sleep(2);
    }
    __syncthreads();

    // ================= phase C: fused edge pipeline =================
    unsigned char* WBs = SM;                                        // 20480
    unsigned short (*actb)[64 * 68] =
        (unsigned short (*)[64 * 68])(SM + 20480);                  // 34816
    int*   sdb = (int*)(SM + 20480 + 34816);                        // 1024
    float (*shb)[64 * 8] =
        (float (*)[64 * 8])(SM + 20480 + 34816 + 1024);             // 8192

    const int wave = tid >> 6;
    const int lane = tid & 63;
    const int q    = lane >> 4;
    const int n    = lane & 15;
    const int i    = blk * 256 + wave * 64 + lane;

    // ---- stage weight fragments (block-shared, 1280 x 16B) ----
#pragma unroll
    for (int it = 0; it < 5; ++it) {
        int idx = it * 256 + tid;
        const unsigned short* gp = Wg + idx * 8;
        unsigned char* lb = WBs + (it * 256 + wave * 64) * 16;
        __builtin_amdgcn_global_load_lds(
            (const __attribute__((address_space(1))) unsigned int*)gp,
            (__attribute__((address_space(3))) unsigned int*)lb, 16, 0, 0);
    }

    unsigned short* actw = actb[wave];

    // ---- geometry (1 lane = 1 edge); sortidx via agent-scope load ----
    int e = __hip_atomic_load(&sortidx[i], __ATOMIC_RELAXED,
                              __HIP_MEMORY_SCOPE_AGENT);
    int s = esrc[e], d = edst[e];
    sdb[wave * 64 + lane] = s | (d << 16);
    int b = batch[s];
    const float* C = cell + b * 9;
    float sx = shifts[e * 3 + 0], sy = shifts[e * 3 + 1], sz = shifts[e * 3 + 2];
    float vx = pos[d * 3 + 0] - pos[s * 3 + 0] + sx * C[0] + sy * C[3] + sz * C[6];
    float vy = pos[d * 3 + 1] - pos[s * 3 + 1] + sx * C[1] + sy * C[4] + sz * C[7];
    float vz = pos[d * 3 + 2] - pos[s * 3 + 2] + sx * C[2] + sy * C[5] + sz * C[8];
    float len = sqrtf(vx * vx + vy * vy + vz * vz);
    float inv = 1.0f / fmaxf(len, 1e-9f);
    float ux = vx * inv, uy = vy * inv, uz = vz * inv;
    {
        const float s3c  = 1.7320508075688772f;
        const float s5c  = 2.2360679774997896f;
        const float s15c = 3.872983346207417f;
        float* shw = shb[wave];
        *(float4*)&shw[lane * 8]     = float4{s3c * ux, s3c * uy, s3c * uz,
                                              s15c * ux * uz};
        *(float4*)&shw[lane * 8 + 4] = float4{s15c * ux * uy,
                                              s5c * (uy * uy - 0.5f * (ux * ux + uz * uz)),
                                              s15c * uy * uz,
                                              0.5f * s15c * (uz * uz - ux * ux)};
    }

    // soft_one_hot (sqrt(10) cancels with fc_W1's /sqrt(10))
    float embv[10];
    float base = len * 2.75f;
#pragma unroll
    for (int ii = 0; ii < 10; ++ii) {
        float ddv = base - (float)(ii + 1);
        embv[ii] = __expf(-ddv * ddv) * (1.0f / 1.12f);
    }
    {
        unsigned int u0 = pk_bf16(embv[0], embv[1]);
        unsigned int u1 = pk_bf16(embv[2], embv[3]);
        unsigned int u2 = pk_bf16(embv[4], embv[5]);
        unsigned int u3 = pk_bf16(embv[6], embv[7]);
        unsigned int u4 = pk_bf16(embv[8], embv[9]);
        uint2* arow = (uint2*)&actw[lane * 68];
        arow[0] = uint2{u0, u1};
        arow[1] = uint2{u2, u3};
        arow[2] = uint2{u4, 0u};
        arow[3] = uint2{0u, 0u};
        arow[4] = uint2{0u, 0u};
        arow[5] = uint2{0u, 0u};
        arow[6] = uint2{0u, 0u};
        arow[7] = uint2{0u, 0u};
    }

    __syncthreads();   // weights staged; sdb written

    union AF { unsigned int u[4]; short8 s8; };
    const f32x4 Z4 = (f32x4){0.f, 0.f, 0.f, 0.f};
    const unsigned short* Wbuf = (const unsigned short*)WBs;

    auto loadA = [&](int t, int kf) -> AF {
        const unsigned short* ap = &actw[(t * 16 + n) * 68 + kf * 32 + q * 8];
        uint2 a = *(const uint2*)ap;
        uint2 c = *(const uint2*)(ap + 4);
        AF f; f.u[0] = a.x; f.u[1] = a.y; f.u[2] = c.x; f.u[3] = c.y;
        return f;
    };
    auto loadW = [&](int f) -> short8 {
        return *(const short8*)&Wbuf[(f * 64 + lane) * 8];
    };

    // ---- layer 1: K=32 (padded emb), N=64 ----
    {
        AF A1[4];
#pragma unroll
        for (int t = 0; t < 4; ++t) A1[t] = loadA(t, 0);
#pragma unroll
        for (int nt = 0; nt < 4; ++nt) {
            short8 W0 = loadW(nt);
            f32x4 Cc[4];
#pragma unroll
            for (int t = 0; t < 4; ++t)
                Cc[t] = __builtin_amdgcn_mfma_f32_16x16x32_bf16(A1[t].s8, W0, Z4, 0, 0, 0);
#pragma unroll
            for (int t = 0; t < 4; ++t)
#pragma unroll
                for (int r = 0; r < 4; ++r)
                    actw[(t * 16 + q * 4 + r) * 68 + nt * 16 + n] = f2bf(silu_f(Cc[t][r]));
        }
    }

    // ---- layer 2: K=64 ----
    {
        AF A2[4][2];
#pragma unroll
        for (int t = 0; t < 4; ++t)
#pragma unroll
            for (int kf = 0; kf < 2; ++kf) A2[t][kf] = loadA(t, kf);
#pragma unroll
        for (int nt = 0; nt < 4; ++nt) {
            short8 Wk0 = loadW(4 + nt);
            short8 Wk1 = loadW(8 + nt);
            f32x4 Cc[4];
#pragma unroll
            for (int t = 0; t < 4; ++t) {
                Cc[t] = __builtin_amdgcn_mfma_f32_16x16x32_bf16(A2[t][0].s8, Wk0, Z4, 0, 0, 0);
                Cc[t] = __builtin_amdgcn_mfma_f32_16x16x32_bf16(A2[t][1].s8, Wk1, Cc[t], 0, 0, 0);
            }
#pragma unroll
            for (int t = 0; t < 4; ++t)
#pragma unroll
                for (int r = 0; r < 4; ++r)
                    actw[(t * 16 + q * 4 + r) * 68 + nt * 16 + n] = f2bf(silu_f(Cc[t][r] * 0.125f));
        }
    }

    // ---- layer 3: K=64, epilogue -> w3 transposed [k][edge] in actw ----
    {
        AF A3[4][2];
#pragma unroll
        for (int t = 0; t < 4; ++t)
#pragma unroll
            for (int kf = 0; kf < 2; ++kf) A3[t][kf] = loadA(t, kf);
#pragma unroll
        for (int nt = 0; nt < 4; ++nt) {
            short8 Wk0 = loadW(12 + nt);
            short8 Wk1 = loadW(16 + nt);
            f32x4 Cc[4];
#pragma unroll
            for (int t = 0; t < 4; ++t) {
                Cc[t] = __builtin_amdgcn_mfma_f32_16x16x32_bf16(A3[t][0].s8, Wk0, Z4, 0, 0, 0);
                Cc[t] = __builtin_amdgcn_mfma_f32_16x16x32_bf16(A3[t][1].s8, Wk1, Cc[t], 0, 0, 0);
            }
#pragma unroll
            for (int t = 0; t < 4; ++t)
#pragma unroll
                for (int r = 0; r < 4; ++r)
                    actw[(nt * 16 + n) * 68 + t * 16 + q * 4 + r] = f2bf(silu_f(Cc[t][r] * 0.125f));
        }
    }

    __syncthreads();   // all waves done with Wbuf -> WBs reusable as B dbuf

    auto stageB = [&](int c, int buf) {
#pragma unroll
        for (int it = 0; it < 2; ++it) {
            int idx = it * 256 + tid;
            const unsigned char* gp = ((const unsigned char*)Bg) + c * 8192 + idx * 16;
            unsigned char* lb = WBs + buf * 8192 + (it * 256 + wave * 64) * 16;
            __builtin_amdgcn_global_load_lds(
                (const __attribute__((address_space(1))) unsigned int*)gp,
                (__attribute__((address_space(3))) unsigned int*)lb, 16, 0, 0);
        }
    };
    stageB(0, 0);

    // k-invariant P fragments: P[e, uv=h*32+q*8+j] = As[h*4+q]*Ad[j]
    AF P[4][2];
#pragma unroll
    for (int t = 0; t < 4; ++t) {
        int eL = wave * 64 + t * 16 + n;
        int sd = sdb[eL];
        int ss  = sd & 0xFFFF;
        int dd2 = sd >> 16;
        float As0 = Ai[ss * 8 + q];
        float As1 = Ai[ss * 8 + 4 + q];
        float4 d0 = *(const float4*)&Ai[dd2 * 8];
        float4 d1 = *(const float4*)&Ai[dd2 * 8 + 4];
        float Ad[8] = {d0.x, d0.y, d0.z, d0.w, d1.x, d1.y, d1.z, d1.w};
#pragma unroll
        for (int h = 0; h < 2; ++h) {
            float s0 = h ? As1 : As0;
            P[t][h].u[0] = pk_bf16(s0 * Ad[0], s0 * Ad[1]);
            P[t][h].u[1] = pk_bf16(s0 * Ad[2], s0 * Ad[3]);
            P[t][h].u[2] = pk_bf16(s0 * Ad[4], s0 * Ad[5]);
            P[t][h].u[3] = pk_bf16(s0 * Ad[6], s0 * Ad[7]);
        }
    }

    f32x4 out[4][2];
#pragma unroll
    for (int t = 0; t < 4; ++t)
#pragma unroll
        for (int nt = 0; nt < 2; ++nt)
            out[t][nt] = (f32x4){0.f, 0.f, 0.f, 0.f};

    __syncthreads();   // chunk 0 resident

#pragma unroll 1
    for (int c = 0; c < 32; ++c) {
        int cur = c & 1;
        if (c < 31) stageB(c + 1, cur ^ 1);
#pragma unroll
        for (int kk = 0; kk < 2; ++kk) {
            int k = c * 2 + kk;
            short8 Bf[2][2];
#pragma unroll
            for (int h = 0; h < 2; ++h)
#pragma unroll
                for (int nt = 0; nt < 2; ++nt)
                    Bf[h][nt] = *(const short8*)(WBs + cur * 8192 +
                                 ((kk * 2 + h) * 2 + nt) * 1024 + lane * 16);
#pragma unroll
            for (int t = 0; t < 4; ++t) {
                uint2 v = *(const uint2*)&actw[k * 68 + t * 16 + q * 4];
                float w0 = __uint_as_float(v.x << 16);
                float w1 = __uint_as_float(v.x & 0xFFFF0000u);
                float w2 = __uint_as_float(v.y << 16);
                float w3 = __uint_as_float(v.y & 0xFFFF0000u);
#pragma unroll
                for (int nt = 0; nt < 2; ++nt) {
                    f32x4 Q = __builtin_amdgcn_mfma_f32_16x16x32_bf16(
                        P[t][0].s8, Bf[0][nt], Z4, 0, 0, 0);
                    Q = __builtin_amdgcn_mfma_f32_16x16x32_bf16(
                        P[t][1].s8, Bf[1][nt], Q, 0, 0, 0);
                    out[t][nt][0] += w0 * Q[0];
                    out[t][nt][1] += w1 * Q[1];
                    out[t][nt][2] += w2 * Q[2];
                    out[t][nt][3] += w3 * Q[3];
                }
            }
        }
        __syncthreads();
    }

    // ---- epilogue: feat rows -> LDS (stride 33), per-wave segmented
    // reduction using the precomputed sh table ----
    float* featL = (float*)actw;   // [64][33] fp32 = 8448 B
#pragma unroll
    for (int t = 0; t < 4; ++t) {
#pragma unroll
        for (int r = 0; r < 4; ++r) {
            int row = t * 16 + q * 4 + r;
            featL[row * 33 + n]      = out[t][0][r];
            featL[row * 33 + 16 + n] = out[t][1][r];
        }
    }
    // same-wave ds write->read: lockstep + compiler lgkmcnt, no barrier needed

    if (lane < 60) {
        int j = lane;
        int cc, sidx = 0;
        bool is0 = (j < 16);
        if (j < 16)      { cc = j; }
        else if (j < 40) { cc = 16 + (j - 16) / 3; sidx = (j - 16) % 3; }
        else             { cc = 24 + (j - 40) / 5; sidx = 3 + (j - 40) % 5; }

        const float* shw = shb[wave];
        int cur_d = sdb[wave * 64] >> 16;
        float acc = 0.f;
        for (int e2 = 0; e2 < 64; ++e2) {
            int d_e = sdb[wave * 64 + e2] >> 16;   // wave-uniform
            if (d_e != cur_d) {
                int cnt = hist[cur_d];
                atomicAdd(&out_g[cur_d * 60 + j], acc * (1.0f / 64.0f) / (float)cnt);
                acc = 0.f;
                cur_d = d_e;
            }
            float f  = featL[e2 * 33 + cc];
            float sh = shw[e2 * 8 + sidx];
            if (is0) sh = 1.0f;
            acc += f * sh;
        }
        int cnt = hist[cur_d];
        atomicAdd(&out_g[cur_d * 60 + j], acc * (1.0f / 64.0f) / (float)cnt);
    }
}

extern "C" void kernel_launch(void* const* d_in, const int* in_sizes, int n_in,
                              void* d_out, int out_size, void* d_ws, size_t ws_size,
                              hipStream_t stream)
{
    const float* pos     = (const float*)d_in[0];
    const int*   A       = (const int*)d_in[1];
    const int*   batch   = (const int*)d_in[2];
    const int*   esrc    = (const int*)d_in[3];
    const int*   edst    = (const int*)d_in[4];
    const float* shifts  = (const float*)d_in[5];
    const float* cell    = (const float*)d_in[6];
    const float* emb_tab = (const float*)d_in[7];
    const float* fitW1   = (const float*)d_in[8];
    const float* fitb1   = (const float*)d_in[9];
    const float* fitW2   = (const float*)d_in[10];
    const float* fitb2   = (const float*)d_in[11];
    const float* fitW3   = (const float*)d_in[12];
    const float* fitb3   = (const float*)d_in[13];
    const float* fcW1    = (const float*)d_in[14];
    const float* fcW2    = (const float*)d_in[15];
    const float* fcW3    = (const float*)d_in[16];
    const float* fcW4    = (const float*)d_in[17];

    float* out = (float*)d_out;

    // workspace layout (hist/poscnt/bar contiguous so one memset covers them)
    char* W = (char*)d_ws;
    float* Ai      = (float*)W;  W += (size_t)NN * 8 * 4;        // 320000
    int* sortidx   = (int*)W;    W += (size_t)NE * 4;            // 524288
    int* hist      = (int*)W;    W += (size_t)NN * 4;            // 40000
    int* poscnt    = (int*)W;    W += (size_t)NN * 4;            // 40000
    int* bar       = (int*)W;    W += 16;                        // 16
    unsigned short* Bg = (unsigned short*)W; W += (size_t)131072 * 2;
    unsigned short* Wg = (unsigned short*)W; W += (size_t)10240 * 2;

    // D0a: zero hist + poscnt + bar (contiguous)
    hipMemsetAsync(hist, 0, (size_t)NN * 4 * 2 + 16, stream);
    // D0b: zero out (600000 floats)
    hipMemsetAsync(out, 0, (size_t)600000 * 4, stream);

    // D1: everything else in one kernel with two fence-free device barriers
    mega2_kernel<<<NE / 256, 256, 0, stream>>>(
        pos, A, batch, esrc, edst, shifts, cell, emb_tab,
        fitW1, fitb1, fitW2, fitb2, fitW3, fitb3,
        fcW1, fcW2, fcW3, fcW4,
        hist, poscnt, bar, Ai, Wg, Bg, sortidx, out);
}

// Round 7
// 192.347 us; speedup vs baseline: 1.2992x; 1.2681x over previous
//
#include <hip/hip_runtime.h>
#include <hip/hip_bf16.h>
#include <math.h>

#define NN 10000
#define NE 131072

typedef __attribute__((ext_vector_type(8))) short short8;
typedef __attribute__((ext_vector_type(4))) float f32x4;

__device__ __forceinline__ float silu_f(float x) {
    return x / (1.0f + __expf(-x));
}

// round-to-nearest-even f32 -> bf16 (finite inputs only)
__device__ __forceinline__ unsigned short f2bf(float f) {
    unsigned int u = __float_as_uint(f);
    u += 0x7FFFu + ((u >> 16) & 1u);
    return (unsigned short)(u >> 16);
}

// packed pair via HW v_cvt_pk_bf16_f32 (x = low half)
__device__ __forceinline__ unsigned int pk_bf16(float lo, float hi) {
    __hip_bfloat162 h = __float22bfloat162_rn(float2{lo, hi});
    return *reinterpret_cast<unsigned int*>(&h);
}

// ---------------------------------------------------------------------------
// D1: prep (692 blocks).  hist already zeroed by D0 memset.
//   [0,40)    node MLP (Ai)
//   [40,80)   prep_W  (fc_W1/2/3 -> bf16 MFMA B-fragments, 10240 elems)
//   [80,592)  prep_B (coalesced fcW4 read -> scattered Bg write)
//             + histogram atomicAdd, STORING the returned rank per edge
//   [592,692) zero out (600000 floats as float4)
// ---------------------------------------------------------------------------
__global__ __launch_bounds__(256)
void prep_kernel(const int* __restrict__ A,
                 const int* __restrict__ edst,
                 const float* __restrict__ emb_tab,
                 const float* __restrict__ W1, const float* __restrict__ b1,
                 const float* __restrict__ W2, const float* __restrict__ b2,
                 const float* __restrict__ W3, const float* __restrict__ b3,
                 const float* __restrict__ fcW1,
                 const float* __restrict__ fcW2,
                 const float* __restrict__ fcW3,
                 const float* __restrict__ fcW4,
                 int* __restrict__ hist,
                 int* __restrict__ rank,
                 float* __restrict__ outg,
                 float* __restrict__ Ai,
                 unsigned short* __restrict__ Wg,
                 unsigned short* __restrict__ Bg)
{
    const int blk = blockIdx.x;
    const int tid = threadIdx.x;

    if (blk < 40) {
        // node MLP -> Ai
        int nd = blk * 256 + tid;
        if (nd >= NN) return;
        int a = A[nd];
        float h[16];
#pragma unroll
        for (int i = 0; i < 16; ++i) h[i] = emb_tab[a * 16 + i];
        float h1[64];
#pragma unroll
        for (int j = 0; j < 64; ++j) h1[j] = b1[j];
#pragma unroll
        for (int i = 0; i < 16; ++i) {
            float hv = h[i];
#pragma unroll
            for (int j = 0; j < 64; ++j) h1[j] += hv * W1[i * 64 + j];
        }
#pragma unroll
        for (int j = 0; j < 64; ++j) h1[j] = silu_f(h1[j]);
        float h2[32];
#pragma unroll
        for (int j = 0; j < 32; ++j) h2[j] = b2[j];
#pragma unroll
        for (int i = 0; i < 64; ++i) {
            float hv = h1[i];
#pragma unroll
            for (int j = 0; j < 32; ++j) h2[j] += hv * W2[i * 32 + j];
        }
#pragma unroll
        for (int j = 0; j < 32; ++j) h2[j] = silu_f(h2[j]);
#pragma unroll
        for (int j = 0; j < 8; ++j) {
            float s = b3[j];
#pragma unroll
            for (int i = 0; i < 32; ++i) s += h2[i] * W3[i * 8 + j];
            Ai[nd * 8 + j] = s;
        }
    } else if (blk < 80) {
        // prep_W: 20 frags of 512 bf16. Element (lane,j):
        //   B[k = kf*32 + (lane>>4)*8 + j][col = nt*16 + (lane&15)]
        int i = (blk - 40) * 256 + tid;   // [0, 10240)
        int j    = i & 7;
        int lane = (i >> 3) & 63;
        int f    = i >> 9;
        int q = lane >> 4, n = lane & 15;
        int L, kf, nt;
        if (f < 4)       { L = 1; kf = 0;             nt = f; }
        else if (f < 12) { L = 2; kf = (f - 4) >> 2;  nt = (f - 4) & 3; }
        else             { L = 3; kf = (f - 12) >> 2; nt = (f - 12) & 3; }
        int k = kf * 32 + q * 8 + j;
        int col = nt * 16 + n;
        float v = 0.0f;
        if (L == 1)      { if (k < 10) v = fcW1[k * 64 + col]; }
        else if (L == 2) v = fcW2[k * 64 + col];
        else             v = fcW3[k * 64 + col];
        Wg[i] = f2bf(v);
    } else if (blk < 592) {
        // prep_B inverse-mapped: coalesced fcW4 stream read, scattered Bg
        // write.  Histogram atomicAdd; the OLD value is this edge's rank
        // within its dst bin (coalesced store) -> scanrank needs no atomics.
        int linear = (blk - 80) * 256 + tid;   // [0, 131072)
        rank[linear] = atomicAdd(&hist[edst[linear]], 1);
        if (linear < 114688) {                 // 64 * 1792 real elements
            int k = linear / 1792;
            int t = linear - k * 1792;
            int uv, wc;
            if (t < 1024)      { uv = t >> 4;            wc = t & 15; }
            else if (t < 1536) { int r = t - 1024; uv = r >> 3; wc = 16 + (r & 7); }
            else               { int r = t - 1536; uv = r >> 2; wc = 24 + (r & 3); }
            int h  = uv >> 5;
            int q  = (uv >> 3) & 3;
            int j  = uv & 7;
            int nt = wc >> 4;
            int n  = wc & 15;
            int i  = (k << 11) | (h << 10) | (nt << 9) | (((q << 4) | n) << 3) | j;
            Bg[i] = f2bf(fcW4[linear]);
        } else {                               // zero padding: wc in [28,32)
            int z  = linear - 114688;          // [0, 16384)
            int k  = z >> 8;
            int r  = z & 255;
            int uv = r >> 2;
            int c2 = z & 3;                    // wc = 28 + c2 -> nt=1, n=12+c2
            int h  = uv >> 5;
            int q  = (uv >> 3) & 3;
            int j  = uv & 7;
            int i  = (k << 11) | (h << 10) | (1 << 9) | (((q << 4) | (12 + c2)) << 3) | j;
            Bg[i] = 0;
        }
    } else {
        // zero out: 600000 floats = 150000 float4
        int t = (blk - 592) * 256 + tid;   // [0, 25600)
        float4 z = float4{0.f, 0.f, 0.f, 0.f};
        for (int r = t; r < 150000; r += 25600)
            ((float4*)outg)[r] = z;
    }
}

// ---------------------------------------------------------------------------
// D2: scan+scatter (512 blocks).  Every block redundantly computes the full
// exclusive scan of hist into LDS (hist reads L2/L3-cached; 20 MB aggregate
// ~ free), then scatters its own 256 edges using the PRECOMPUTED rank --
// zero atomics here.  hist stays intact (counts for the edge epilogue).
// ---------------------------------------------------------------------------
__global__ __launch_bounds__(256)
void scanrank_kernel(const int* __restrict__ edst,
                     const int* __restrict__ hist,
                     const int* __restrict__ rank,
                     int* __restrict__ sortidx)
{
    __shared__ int offs[NN];    // 40000 B
    __shared__ int part[256];
    const int tid = threadIdx.x;

    int loc[40];
    int s = 0;
    if (tid < 250) {            // 250*40 = 10000 bins exactly
        const int4* h4 = (const int4*)(hist) + tid * 10;
#pragma unroll
        for (int v = 0; v < 10; ++v) {
            int4 x = h4[v];
            loc[v * 4 + 0] = x.x; loc[v * 4 + 1] = x.y;
            loc[v * 4 + 2] = x.z; loc[v * 4 + 3] = x.w;
            s += x.x + x.y + x.z + x.w;
        }
    } else {
#pragma unroll
        for (int r = 0; r < 40; ++r) loc[r] = 0;
    }
    part[tid] = s;
    __syncthreads();
#pragma unroll
    for (int off = 1; off < 256; off <<= 1) {
        int v = (tid >= off) ? part[tid - off] : 0;
        __syncthreads();
        part[tid] += v;
        __syncthreads();
    }
    if (tid < 250) {
        int run = part[tid] - s;   // exclusive prefix of this thread's chunk
        int base = tid * 40;
#pragma unroll
        for (int r = 0; r < 40; ++r) { offs[base + r] = run; run += loc[r]; }
    }
    __syncthreads();

    // scatter this block's 256 edges (coalesced reads, no atomics)
    int e = blockIdx.x * 256 + tid;
    int d = edst[e];
    sortidx[offs[d] + rank[e]] = e;
}

// ---------------------------------------------------------------------------
// D3: fused edge pipeline (byte-identical to the round-4 verified kernel).
// LDS: WBs 20480 + actb 34816 + sdb 1024 + shb 8192 = 64512 B -> 2 blocks/CU.
// ---------------------------------------------------------------------------
__global__ __launch_bounds__(256, 2)
void edge_fused_kernel(const float* __restrict__ pos,
                       const int* __restrict__ batch,
                       const int* __restrict__ esrc,
                       const int* __restrict__ edst,
                       const float* __restrict__ shifts,
                       const float* __restrict__ cell,
                       const unsigned short* __restrict__ Wg,
                       const unsigned short* __restrict__ Bg,
                       const int* __restrict__ sortidx,
                       const float* __restrict__ Ai,
                       const int* __restrict__ hist,
                       float* __restrict__ out_g)
{
    __shared__ __align__(16) unsigned char  WBs[20480];       // Wbuf(20KB) U Bs[2][8KB]
    __shared__ __align__(16) unsigned short actb[4][64 * 68]; // 4 x 8.5 KB
    __shared__ int   sdb[256];                                // packed s | (d<<16)
    __shared__ __align__(16) float shb[4][64 * 8];            // per-edge sh table

    const int tid  = threadIdx.x;
    const int wave = tid >> 6;
    const int lane = tid & 63;
    const int q    = lane >> 4;
    const int n    = lane & 15;
    const int i    = blockIdx.x * 256 + wave * 64 + lane;

    // ---- stage weight fragments (block-shared, 1280 x 16B) ----
#pragma unroll
    for (int it = 0; it < 5; ++it) {
        int idx = it * 256 + tid;
        const unsigned short* gp = Wg + idx * 8;
        unsigned char* lb = WBs + (it * 256 + wave * 64) * 16;
        __builtin_amdgcn_global_load_lds(
            (const __attribute__((address_space(1))) unsigned int*)gp,
            (__attribute__((address_space(3))) unsigned int*)lb, 16, 0, 0);
    }

    unsigned short* actw = actb[wave];

    // ---- geometry (1 lane = 1 edge) ----
    int e = sortidx[i];
    int s = esrc[e], d = edst[e];
    sdb[wave * 64 + lane] = s | (d << 16);
    int b = batch[s];
    const float* C = cell + b * 9;
    float sx = shifts[e * 3 + 0], sy = shifts[e * 3 + 1], sz = shifts[e * 3 + 2];
    float vx = pos[d * 3 + 0] - pos[s * 3 + 0] + sx * C[0] + sy * C[3] + sz * C[6];
    float vy = pos[d * 3 + 1] - pos[s * 3 + 1] + sx * C[1] + sy * C[4] + sz * C[7];
    float vz = pos[d * 3 + 2] - pos[s * 3 + 2] + sx * C[2] + sy * C[5] + sz * C[8];
    float len = sqrtf(vx * vx + vy * vy + vz * vz);
    float inv = 1.0f / fmaxf(len, 1e-9f);
    float ux = vx * inv, uy = vy * inv, uz = vz * inv;
    {
        const float s3c  = 1.7320508075688772f;
        const float s5c  = 2.2360679774997896f;
        const float s15c = 3.872983346207417f;
        float* shw = shb[wave];
        *(float4*)&shw[lane * 8]     = float4{s3c * ux, s3c * uy, s3c * uz,
                                              s15c * ux * uz};
        *(float4*)&shw[lane * 8 + 4] = float4{s15c * ux * uy,
                                              s5c * (uy * uy - 0.5f * (ux * ux + uz * uz)),
                                              s15c * uy * uz,
                                              0.5f * s15c * (uz * uz - ux * ux)};
    }

    // soft_one_hot (sqrt(10) cancels with fc_W1's /sqrt(10))
    float embv[10];
    float base = len * 2.75f;
#pragma unroll
    for (int ii = 0; ii < 10; ++ii) {
        float ddv = base - (float)(ii + 1);
        embv[ii] = __expf(-ddv * ddv) * (1.0f / 1.12f);
    }
    {
        unsigned int u0 = pk_bf16(embv[0], embv[1]);
        unsigned int u1 = pk_bf16(embv[2], embv[3]);
        unsigned int u2 = pk_bf16(embv[4], embv[5]);
        unsigned int u3 = pk_bf16(embv[6], embv[7]);
        unsigned int u4 = pk_bf16(embv[8], embv[9]);
        uint2* arow = (uint2*)&actw[lane * 68];
        arow[0] = uint2{u0, u1};
        arow[1] = uint2{u2, u3};
        arow[2] = uint2{u4, 0u};
        arow[3] = uint2{0u, 0u};
        arow[4] = uint2{0u, 0u};
        arow[5] = uint2{0u, 0u};
        arow[6] = uint2{0u, 0u};
        arow[7] = uint2{0u, 0u};
    }

    __syncthreads();   // weights staged; sdb written

    union AF { unsigned int u[4]; short8 s8; };
    const f32x4 Z4 = (f32x4){0.f, 0.f, 0.f, 0.f};
    const unsigned short* Wbuf = (const unsigned short*)WBs;

    auto loadA = [&](int t, int kf) -> AF {
        const unsigned short* ap = &actw[(t * 16 + n) * 68 + kf * 32 + q * 8];
        uint2 a = *(const uint2*)ap;
        uint2 c = *(const uint2*)(ap + 4);
        AF f; f.u[0] = a.x; f.u[1] = a.y; f.u[2] = c.x; f.u[3] = c.y;
        return f;
    };
    auto loadW = [&](int f) -> short8 {
        return *(const short8*)&Wbuf[(f * 64 + lane) * 8];
    };

    // ---- layer 1: K=32 (padded emb), N=64 ----
    {
        AF A1[4];
#pragma unroll
        for (int t = 0; t < 4; ++t) A1[t] = loadA(t, 0);
#pragma unroll
        for (int nt = 0; nt < 4; ++nt) {
            short8 W0 = loadW(nt);
            f32x4 Cc[4];
#pragma unroll
            for (int t = 0; t < 4; ++t)
                Cc[t] = __builtin_amdgcn_mfma_f32_16x16x32_bf16(A1[t].s8, W0, Z4, 0, 0, 0);
#pragma unroll
            for (int t = 0; t < 4; ++t)
#pragma unroll
                for (int r = 0; r < 4; ++r)
                    actw[(t * 16 + q * 4 + r) * 68 + nt * 16 + n] = f2bf(silu_f(Cc[t][r]));
        }
    }

    // ---- layer 2: K=64 ----
    {
        AF A2[4][2];
#pragma unroll
        for (int t = 0; t < 4; ++t)
#pragma unroll
            for (int kf = 0; kf < 2; ++kf) A2[t][kf] = loadA(t, kf);
#pragma unroll
        for (int nt = 0; nt < 4; ++nt) {
            short8 Wk0 = loadW(4 + nt);
            short8 Wk1 = loadW(8 + nt);
            f32x4 Cc[4];
#pragma unroll
            for (int t = 0; t < 4; ++t) {
                Cc[t] = __builtin_amdgcn_mfma_f32_16x16x32_bf16(A2[t][0].s8, Wk0, Z4, 0, 0, 0);
                Cc[t] = __builtin_amdgcn_mfma_f32_16x16x32_bf16(A2[t][1].s8, Wk1, Cc[t], 0, 0, 0);
            }
#pragma unroll
            for (int t = 0; t < 4; ++t)
#pragma unroll
                for (int r = 0; r < 4; ++r)
                    actw[(t * 16 + q * 4 + r) * 68 + nt * 16 + n] = f2bf(silu_f(Cc[t][r] * 0.125f));
        }
    }

    // ---- layer 3: K=64, epilogue -> w3 transposed [k][edge] in actw ----
    {
        AF A3[4][2];
#pragma unroll
        for (int t = 0; t < 4; ++t)
#pragma unroll
            for (int kf = 0; kf < 2; ++kf) A3[t][kf] = loadA(t, kf);
#pragma unroll
        for (int nt = 0; nt < 4; ++nt) {
            short8 Wk0 = loadW(12 + nt);
            short8 Wk1 = loadW(16 + nt);
            f32x4 Cc[4];
#pragma unroll
            for (int t = 0; t < 4; ++t) {
                Cc[t] = __builtin_amdgcn_mfma_f32_16x16x32_bf16(A3[t][0].s8, Wk0, Z4, 0, 0, 0);
                Cc[t] = __builtin_amdgcn_mfma_f32_16x16x32_bf16(A3[t][1].s8, Wk1, Cc[t], 0, 0, 0);
            }
#pragma unroll
            for (int t = 0; t < 4; ++t)
#pragma unroll
                for (int r = 0; r < 4; ++r)
                    actw[(nt * 16 + n) * 68 + t * 16 + q * 4 + r] = f2bf(silu_f(Cc[t][r] * 0.125f));
        }
    }

    __syncthreads();   // all waves done with Wbuf -> WBs reusable as B dbuf

    auto stageB = [&](int c, int buf) {
#pragma unroll
        for (int it = 0; it < 2; ++it) {
            int idx = it * 256 + tid;
            const unsigned char* gp = ((const unsigned char*)Bg) + c * 8192 + idx * 16;
            unsigned char* lb = WBs + buf * 8192 + (it * 256 + wave * 64) * 16;
            __builtin_amdgcn_global_load_lds(
                (const __attribute__((address_space(1))) unsigned int*)gp,
                (__attribute__((address_space(3))) unsigned int*)lb, 16, 0, 0);
        }
    };
    stageB(0, 0);

    // k-invariant P fragments: P[e, uv=h*32+q*8+j] = As[h*4+q]*Ad[j]
    AF P[4][2];
#pragma unroll
    for (int t = 0; t < 4; ++t) {
        int eL = wave * 64 + t * 16 + n;
        int sd = sdb[eL];
        int ss  = sd & 0xFFFF;
        int dd2 = sd >> 16;
        float As0 = Ai[ss * 8 + q];
        float As1 = Ai[ss * 8 + 4 + q];
        float4 d0 = *(const float4*)&Ai[dd2 * 8];
        float4 d1 = *(const float4*)&Ai[dd2 * 8 + 4];
        float Ad[8] = {d0.x, d0.y, d0.z, d0.w, d1.x, d1.y, d1.z, d1.w};
#pragma unroll
        for (int h = 0; h < 2; ++h) {
            float s0 = h ? As1 : As0;
            P[t][h].u[0] = pk_bf16(s0 * Ad[0], s0 * Ad[1]);
            P[t][h].u[1] = pk_bf16(s0 * Ad[2], s0 * Ad[3]);
            P[t][h].u[2] = pk_bf16(s0 * Ad[4], s0 * Ad[5]);
            P[t][h].u[3] = pk_bf16(s0 * Ad[6], s0 * Ad[7]);
        }
    }

    f32x4 out[4][2];
#pragma unroll
    for (int t = 0; t < 4; ++t)
#pragma unroll
        for (int nt = 0; nt < 2; ++nt)
            out[t][nt] = (f32x4){0.f, 0.f, 0.f, 0.f};

    __syncthreads();   // chunk 0 resident

#pragma unroll 1
    for (int c = 0; c < 32; ++c) {
        int cur = c & 1;
        if (c < 31) stageB(c + 1, cur ^ 1);
#pragma unroll
        for (int kk = 0; kk < 2; ++kk) {
            int k = c * 2 + kk;
            short8 Bf[2][2];
#pragma unroll
            for (int h = 0; h < 2; ++h)
#pragma unroll
                for (int nt = 0; nt < 2; ++nt)
                    Bf[h][nt] = *(const short8*)(WBs + cur * 8192 +
                                 ((kk * 2 + h) * 2 + nt) * 1024 + lane * 16);
#pragma unroll
            for (int t = 0; t < 4; ++t) {
                uint2 v = *(const uint2*)&actw[k * 68 + t * 16 + q * 4];
                float w0 = __uint_as_float(v.x << 16);
                float w1 = __uint_as_float(v.x & 0xFFFF0000u);
                float w2 = __uint_as_float(v.y << 16);
                float w3 = __uint_as_float(v.y & 0xFFFF0000u);
#pragma unroll
                for (int nt = 0; nt < 2; ++nt) {
                    f32x4 Q = __builtin_amdgcn_mfma_f32_16x16x32_bf16(
                        P[t][0].s8, Bf[0][nt], Z4, 0, 0, 0);
                    Q = __builtin_amdgcn_mfma_f32_16x16x32_bf16(
                        P[t][1].s8, Bf[1][nt], Q, 0, 0, 0);
                    out[t][nt][0] += w0 * Q[0];
                    out[t][nt][1] += w1 * Q[1];
                    out[t][nt][2] += w2 * Q[2];
                    out[t][nt][3] += w3 * Q[3];
                }
            }
        }
        __syncthreads();
    }

    // ---- epilogue: feat rows -> LDS (stride 33), per-wave segmented
    // reduction using the precomputed sh table ----
    float* featL = (float*)actw;   // [64][33] fp32 = 8448 B
#pragma unroll
    for (int t = 0; t < 4; ++t) {
#pragma unroll
        for (int r = 0; r < 4; ++r) {
            int row = t * 16 + q * 4 + r;
            featL[row * 33 + n]      = out[t][0][r];
            featL[row * 33 + 16 + n] = out[t][1][r];
        }
    }
    // same-wave ds write->read: lockstep + compiler lgkmcnt, no barrier needed

    if (lane < 60) {
        int j = lane;
        int cc, sidx = 0;
        bool is0 = (j < 16);
        if (j < 16)      { cc = j; }
        else if (j < 40) { cc = 16 + (j - 16) / 3; sidx = (j - 16) % 3; }
        else             { cc = 24 + (j - 40) / 5; sidx = 3 + (j - 40) % 5; }

        const float* shw = shb[wave];
        int cur_d = sdb[wave * 64] >> 16;
        float acc = 0.f;
        for (int e2 = 0; e2 < 64; ++e2) {
            int d_e = sdb[wave * 64 + e2] >> 16;   // wave-uniform
            if (d_e != cur_d) {
                int cnt = hist[cur_d];
                atomicAdd(&out_g[cur_d * 60 + j], acc * (1.0f / 64.0f) / (float)cnt);
                acc = 0.f;
                cur_d = d_e;
            }
            float f  = featL[e2 * 33 + cc];
            float sh = shw[e2 * 8 + sidx];
            if (is0) sh = 1.0f;
            acc += f * sh;
        }
        int cnt = hist[cur_d];
        atomicAdd(&out_g[cur_d * 60 + j], acc * (1.0f / 64.0f) / (float)cnt);
    }
}

extern "C" void kernel_launch(void* const* d_in, const int* in_sizes, int n_in,
                              void* d_out, int out_size, void* d_ws, size_t ws_size,
                              hipStream_t stream)
{
    const float* pos     = (const float*)d_in[0];
    const int*   A       = (const int*)d_in[1];
    const int*   batch   = (const int*)d_in[2];
    const int*   esrc    = (const int*)d_in[3];
    const int*   edst    = (const int*)d_in[4];
    const float* shifts  = (const float*)d_in[5];
    const float* cell    = (const float*)d_in[6];
    const float* emb_tab = (const float*)d_in[7];
    const float* fitW1   = (const float*)d_in[8];
    const float* fitb1   = (const float*)d_in[9];
    const float* fitW2   = (const float*)d_in[10];
    const float* fitb2   = (const float*)d_in[11];
    const float* fitW3   = (const float*)d_in[12];
    const float* fitb3   = (const float*)d_in[13];
    const float* fcW1    = (const float*)d_in[14];
    const float* fcW2    = (const float*)d_in[15];
    const float* fcW3    = (const float*)d_in[16];
    const float* fcW4    = (const float*)d_in[17];

    float* out = (float*)d_out;

    // workspace layout (all 16B-aligned)
    char* W = (char*)d_ws;
    float* Ai      = (float*)W;  W += (size_t)NN * 8 * 4;        // 320000
    int* sortidx   = (int*)W;    W += (size_t)NE * 4;            // 524288
    int* rank      = (int*)W;    W += (size_t)NE * 4;            // 524288
    int* hist      = (int*)W;    W += (size_t)NN * 4;            // 40000
    unsigned short* Bg = (unsigned short*)W; W += (size_t)131072 * 2;
    unsigned short* Wg = (unsigned short*)W; W += (size_t)10240 * 2;

    // D0: zero hist only (rank is fully overwritten by prep)
    hipMemsetAsync(hist, 0, (size_t)NN * 4, stream);

    // D1: prep (MLP, W/B fragment packing, histogram + rank, out zeroing)
    prep_kernel<<<692, 256, 0, stream>>>(
        A, edst, emb_tab, fitW1, fitb1, fitW2, fitb2, fitW3, fitb3,
        fcW1, fcW2, fcW3, fcW4, hist, rank, out, Ai, Wg, Bg);

    // D2: per-block redundant scan + atomic-free scatter
    scanrank_kernel<<<NE / 256, 256, 0, stream>>>(edst, hist, rank, sortidx);

    // D3: fused edge pipeline
    edge_fused_kernel<<<NE / 256, 256, 0, stream>>>(
        pos, batch, esrc, edst, shifts, cell, Wg, Bg,
        sortidx, Ai, hist, out);
}